// Round 10
// baseline (364.054 us; speedup 1.0000x reference)
//
#include <hip/hip_runtime.h>
#include <math.h>

#define N_NODES 50000
#define N_EDGES 500000
#define D_IN 512
#define D_H  512
#define D_OUT 256
#define NB 196  // ceil(N_NODES/256)

typedef __attribute__((ext_vector_type(8))) short bf16x8;
typedef __attribute__((ext_vector_type(8))) unsigned short ushort8;
typedef __attribute__((ext_vector_type(4))) float f32x4;

__device__ __forceinline__ float b2f(unsigned short u) {
    union { unsigned int i; float f; } v; v.i = ((unsigned int)u) << 16; return v.f;
}
__device__ __forceinline__ unsigned short f2b(float f) {
    unsigned int x = __float_as_uint(f);
    unsigned int r = (x + 0x7fffu + ((x >> 16) & 1u)) >> 16;  // RNE
    return (unsigned short)r;
}

// ---------------- x fp32 -> bf16 ----------------

__global__ __launch_bounds__(256) void k_cvt(const float* __restrict__ in,
                                             unsigned short* __restrict__ out,
                                             long long n8) {
    long long i = (long long)blockIdx.x * 256 + threadIdx.x;
    if (i >= n8) return;
    float4 v0 = ((const float4*)in)[i * 2];
    float4 v1 = ((const float4*)in)[i * 2 + 1];
    ushort8 o;
    o[0] = f2b(v0.x); o[1] = f2b(v0.y); o[2] = f2b(v0.z); o[3] = f2b(v0.w);
    o[4] = f2b(v1.x); o[5] = f2b(v1.y); o[6] = f2b(v1.z); o[7] = f2b(v1.w);
    ((ushort8*)out)[i] = o;
}

// ---------------- weight transpose: W [K][N] fp32 -> Wt [N][K] bf16 ----------------

__global__ void k_wt(const float* __restrict__ W, unsigned short* __restrict__ Wt,
                     int K, int N) {
    __shared__ float t[32][33];
    const int bk = blockIdx.x * 32, bn = blockIdx.y * 32;
    const int tx = threadIdx.x, ty = threadIdx.y;  // (32,8)
    for (int i = ty; i < 32; i += 8) t[i][tx] = W[(size_t)(bk + i) * N + bn + tx];
    __syncthreads();
    for (int i = ty; i < 32; i += 8)
        Wt[(size_t)(bn + i) * K + bk + tx] = f2b(t[tx][i]);
}

// ---------------- degree / CSR build ----------------

__global__ __launch_bounds__(256) void k_zero(int* __restrict__ p, int n) {
    int i = blockIdx.x * 256 + threadIdx.x;
    if (i < n) p[i] = 0;
}

__global__ __launch_bounds__(256) void k_indeg(const int* __restrict__ dst,
                                               int* __restrict__ indeg) {
    int i = blockIdx.x * 256 + threadIdx.x;
    if (i < N_EDGES) atomicAdd(&indeg[dst[i]], 1);
}

__global__ __launch_bounds__(256) void k_partials(const int* __restrict__ indeg,
                                                  int* __restrict__ bsum) {
    __shared__ int wsum[4];
    const int tid = threadIdx.x, lane = tid & 63, w = tid >> 6;
    const int i = blockIdx.x * 256 + tid;
    int v = (i < N_NODES) ? indeg[i] : 0;
#pragma unroll
    for (int o = 32; o > 0; o >>= 1) v += __shfl_down(v, o, 64);
    if (lane == 0) wsum[w] = v;
    __syncthreads();
    if (tid == 0) bsum[blockIdx.x] = wsum[0] + wsum[1] + wsum[2] + wsum[3];
}

__global__ __launch_bounds__(256) void k_scanb(const int* __restrict__ bsum,
                                               int* __restrict__ boff) {
    __shared__ int wsum[4];
    const int tid = threadIdx.x, lane = tid & 63, w = tid >> 6;
    const int v = (tid < NB) ? bsum[tid] : 0;
    int s = v;
#pragma unroll
    for (int o = 1; o < 64; o <<= 1) {
        int t = __shfl_up(s, o, 64);
        if (lane >= o) s += t;
    }
    if (lane == 63) wsum[w] = s;
    __syncthreads();
    int add = 0;
    for (int k = 0; k < w; ++k) add += wsum[k];
    if (tid < NB) boff[tid] = add + s - v;
}

__global__ __launch_bounds__(256) void k_finalize(const int* __restrict__ indeg,
                                                  const int* __restrict__ boff,
                                                  int* __restrict__ row_start,
                                                  int* __restrict__ cursor,
                                                  float* __restrict__ dinv) {
    __shared__ int wsum[4];
    const int tid = threadIdx.x, lane = tid & 63, w = tid >> 6;
    const int i = blockIdx.x * 256 + tid;
    const int v = (i < N_NODES) ? indeg[i] : 0;
    int s = v;
#pragma unroll
    for (int o = 1; o < 64; o <<= 1) {
        int t = __shfl_up(s, o, 64);
        if (lane >= o) s += t;
    }
    if (lane == 63) wsum[w] = s;
    __syncthreads();
    int add = boff[blockIdx.x];
    for (int k = 0; k < w; ++k) add += wsum[k];
    if (i < N_NODES) {
        const int excl = add + s - v;
        row_start[i] = excl;
        cursor[i] = excl;
        dinv[i] = rsqrtf((float)(1 + v));
    }
    if (i == N_NODES) row_start[N_NODES] = N_EDGES;
}

__global__ __launch_bounds__(256) void k_bucket(const int* __restrict__ src,
                                                const int* __restrict__ dst,
                                                int* __restrict__ cursor,
                                                int* __restrict__ csr_src) {
    int e = blockIdx.x * 256 + threadIdx.x;
    if (e >= N_EDGES) return;
    int pos = atomicAdd(&cursor[dst[e]], 1);
    csr_src[pos] = src[e];
}

// ---------------- 128x128 bf16 GEMM, BK=64, dbuf, swizzled LDS, vec epilogue ----
// (R9 structure, unchanged: 0 bank conflicts, vectorized dwordx4 C stores.)

__device__ __forceinline__ void gload16(const void* g, void* l) {
    __builtin_amdgcn_global_load_lds(
        (const __attribute__((address_space(1))) unsigned int*)g,
        (__attribute__((address_space(3))) unsigned int*)l, 16, 0, 0);
}

__global__ __launch_bounds__(256, 2) void k_gemm(const unsigned short* __restrict__ A,
                                                 const unsigned short* __restrict__ Bt,
                                                 unsigned short* __restrict__ C,
                                                 int M, int N, int K,
                                                 int ncb, int nrb) {
    __shared__ __align__(16) short As[2][128 * 64];
    __shared__ __align__(16) short Bs[2][128 * 64];

    const int bid = blockIdx.x;
    const int xcd = bid & 7;
    const int sidx = bid >> 3;
    const int cb = sidx % ncb;
    const int rb = (sidx / ncb) * 8 + xcd;
    if (rb >= nrb) return;
    const int brow = rb * 128;
    const int bcol = cb * 128;

    const int tid = threadIdx.x;
    const int wid = tid >> 6;
    const int lane = tid & 63;
    const int wr = wid >> 1, wc = wid & 1;
    const int lhi = lane >> 4, llo = lane & 15;

    f32x4 acc[4][4];
#pragma unroll
    for (int i = 0; i < 4; ++i)
#pragma unroll
        for (int j = 0; j < 4; ++j) acc[i][j] = (f32x4){0.f, 0.f, 0.f, 0.f};

#define STAGE(buf, kt)                                                          \
    {                                                                           \
        _Pragma("unroll") for (int g = 0; g < 4; ++g) {                         \
            const int s = g * 256 + tid;                                        \
            const int row = s >> 3;                                             \
            const int sc = (s & 7) ^ (row & 7);                                 \
            int gr = brow + row; gr = gr < M ? gr : M - 1;                      \
            gload16(A + (size_t)gr * K + (kt) + sc * 8,                         \
                    &As[buf][(g * 256 + wid * 64) * 8]);                        \
            gload16(Bt + (size_t)(bcol + row) * K + (kt) + sc * 8,              \
                    &Bs[buf][(g * 256 + wid * 64) * 8]);                        \
        }                                                                       \
    }

    const int nt = K / 64;

    STAGE(0, 0);
    __syncthreads();

    int cur = 0;
    for (int t = 0; t < nt; ++t) {
        if (t + 1 < nt) STAGE(cur ^ 1, (t + 1) * 64);

#pragma unroll
        for (int ks = 0; ks < 2; ++ks) {
            bf16x8 af[4], bf[4];
#pragma unroll
            for (int mi = 0; mi < 4; ++mi) {
                const int row = wr * 64 + mi * 16 + llo;
                af[mi] = *(const bf16x8*)&As[cur][row * 64 + (((ks * 4 + lhi) ^ (llo & 7)) * 8)];
            }
#pragma unroll
            for (int ni = 0; ni < 4; ++ni) {
                const int row = wc * 64 + ni * 16 + llo;
                bf[ni] = *(const bf16x8*)&Bs[cur][row * 64 + (((ks * 4 + lhi) ^ (llo & 7)) * 8)];
            }
#pragma unroll
            for (int mi = 0; mi < 4; ++mi)
#pragma unroll
                for (int ni = 0; ni < 4; ++ni)
                    acc[mi][ni] = __builtin_amdgcn_mfma_f32_16x16x32_bf16(
                        af[mi], bf[ni], acc[mi][ni], 0, 0, 0);
        }

        __syncthreads();
        cur ^= 1;
    }
#undef STAGE

    // epilogue: per-wave 64x64 swizzled LDS tile -> dwordx4 stores
    short* cws = &As[0][0] + wid * 4096;

#pragma unroll
    for (int mi = 0; mi < 4; ++mi)
#pragma unroll
        for (int ni = 0; ni < 4; ++ni) {
            const f32x4 v = acc[mi][ni];
#pragma unroll
            for (int r = 0; r < 4; ++r) {
                const int row = mi * 16 + lhi * 4 + r;
                const int col = ni * 16 + llo;
                const int chunk = (col >> 3) ^ (row & 7);
                cws[row * 64 + chunk * 8 + (col & 7)] = (short)f2b(v[r]);
            }
        }
    __syncthreads();

    {
        const int rsub = lane >> 3;
        const int c = lane & 7;
#pragma unroll
        for (int i = 0; i < 8; ++i) {
            const int row = i * 8 + rsub;
            const ushort8 o = *(const ushort8*)&cws[row * 64 + ((c ^ (row & 7)) * 8)];
            const int grow = brow + wr * 64 + row;
            if (grow < M)
                *(ushort8*)(C + (size_t)grow * N + bcol + wc * 64 + c * 8) = o;
        }
    }
}

// ---------------- column-chunked aggregate: self + gather + bias + ELU ----------
// 32-col chunks (3.2 MB slice < 4 MiB XCD L2), chunk pinned to XCD via bid&7.
// Block: 256 thr = 4 waves x 8 groups of 8 lanes; group = one node; lane = 4 cols
// (ushort4 = 8B; group reads 64B/edge = one cacheline). NPASS chunks per XCD,
// dispatched pass-major so each XCD streams one 3.2 MB slice at a time.

template <int D, bool BF16_OUT, int NPASS>
__global__ __launch_bounds__(256) void k_agg_chunk(const unsigned short* __restrict__ H,
                                                   const float* __restrict__ bias,
                                                   void* __restrict__ outv,
                                                   const int* __restrict__ row_start,
                                                   const int* __restrict__ csr_src,
                                                   const float* __restrict__ dinv,
                                                   int nbpc) {
    const int bid = blockIdx.x;
    const int xcd = bid & 7;
    const int s = bid >> 3;
    const int pass = s / nbpc;
    const int nb = s % nbpc;
    const int col0 = (pass * 8 + xcd) * 32;

    const int tid = threadIdx.x;
    const int wid = tid >> 6;
    const int lane = tid & 63;
    const int grp = lane >> 3;
    const int lg = lane & 7;

    const int n = nb * 32 + wid * 8 + grp;
    if (n >= N_NODES) return;
    const int c = col0 + lg * 4;

    const float di = dinv[n];
    float a0, a1, a2, a3;
    {
        const float w = di * di;
        ushort4 v = *(const ushort4*)(H + (size_t)n * D + c);
        a0 = b2f(v.x) * w; a1 = b2f(v.y) * w; a2 = b2f(v.z) * w; a3 = b2f(v.w) * w;
    }

    const int e0 = row_start[n];
    const int e1 = row_start[n + 1];
    int j = e0;
    for (; j + 4 <= e1; j += 4) {
        const int s0 = csr_src[j + 0];
        const int s1 = csr_src[j + 1];
        const int s2 = csr_src[j + 2];
        const int s3 = csr_src[j + 3];
        const float w0 = dinv[s0] * di;
        const float w1 = dinv[s1] * di;
        const float w2 = dinv[s2] * di;
        const float w3 = dinv[s3] * di;
        const ushort4 v0 = *(const ushort4*)(H + (size_t)s0 * D + c);
        const ushort4 v1 = *(const ushort4*)(H + (size_t)s1 * D + c);
        const ushort4 v2 = *(const ushort4*)(H + (size_t)s2 * D + c);
        const ushort4 v3 = *(const ushort4*)(H + (size_t)s3 * D + c);
        a0 = fmaf(b2f(v0.x), w0, a0); a1 = fmaf(b2f(v0.y), w0, a1);
        a2 = fmaf(b2f(v0.z), w0, a2); a3 = fmaf(b2f(v0.w), w0, a3);
        a0 = fmaf(b2f(v1.x), w1, a0); a1 = fmaf(b2f(v1.y), w1, a1);
        a2 = fmaf(b2f(v1.z), w1, a2); a3 = fmaf(b2f(v1.w), w1, a3);
        a0 = fmaf(b2f(v2.x), w2, a0); a1 = fmaf(b2f(v2.y), w2, a1);
        a2 = fmaf(b2f(v2.z), w2, a2); a3 = fmaf(b2f(v2.w), w2, a3);
        a0 = fmaf(b2f(v3.x), w3, a0); a1 = fmaf(b2f(v3.y), w3, a1);
        a2 = fmaf(b2f(v3.z), w3, a2); a3 = fmaf(b2f(v3.w), w3, a3);
    }
    for (; j < e1; ++j) {
        const int sx = csr_src[j];
        const float w = dinv[sx] * di;
        const ushort4 v = *(const ushort4*)(H + (size_t)sx * D + c);
        a0 = fmaf(b2f(v.x), w, a0); a1 = fmaf(b2f(v.y), w, a1);
        a2 = fmaf(b2f(v.z), w, a2); a3 = fmaf(b2f(v.w), w, a3);
    }

    const float4 b = *(const float4*)(bias + c);
    a0 += b.x; a1 += b.y; a2 += b.z; a3 += b.w;
    a0 = a0 > 0.f ? a0 : expf(a0) - 1.f;
    a1 = a1 > 0.f ? a1 : expf(a1) - 1.f;
    a2 = a2 > 0.f ? a2 : expf(a2) - 1.f;
    a3 = a3 > 0.f ? a3 : expf(a3) - 1.f;

    if (BF16_OUT) {
        ushort4 o;
        o.x = f2b(a0); o.y = f2b(a1); o.z = f2b(a2); o.w = f2b(a3);
        *(ushort4*)((unsigned short*)outv + (size_t)n * D + c) = o;
    } else {
        *(float4*)((float*)outv + (size_t)n * D + c) = make_float4(a0, a1, a2, a3);
    }
}

// ---------------- launch ----------------

extern "C" void kernel_launch(void* const* d_in, const int* in_sizes, int n_in,
                              void* d_out, int out_size, void* d_ws, size_t ws_size,
                              hipStream_t stream) {
    const float* x  = (const float*)d_in[0];
    const int* ei   = (const int*)d_in[1];
    const int* src  = ei;
    const int* dst  = ei + N_EDGES;
    const float* W1 = (const float*)d_in[2];
    const float* b1 = (const float*)d_in[3];
    const float* W2 = (const float*)d_in[4];
    const float* b2 = (const float*)d_in[5];
    float* out = (float*)d_out;

    char* ws = (char*)d_ws;
    size_t off = 0;
    auto alloc = [&](size_t bytes) -> void* {
        void* p = ws + off;
        off = (off + bytes + 255) & ~(size_t)255;
        return p;
    };
    int*   indeg     = (int*)alloc((size_t)N_NODES * 4);
    int*   bsum      = (int*)alloc((size_t)NB * 4);
    int*   boff      = (int*)alloc((size_t)NB * 4);
    int*   row_start = (int*)alloc((size_t)(N_NODES + 1) * 4);
    int*   cursor    = (int*)alloc((size_t)N_NODES * 4);
    int*   csr_src   = (int*)alloc((size_t)N_EDGES * 4);
    float* dinv      = (float*)alloc((size_t)N_NODES * 4);
    unsigned short* W1t  = (unsigned short*)alloc((size_t)D_H * D_IN * 2);
    unsigned short* W2t  = (unsigned short*)alloc((size_t)D_OUT * D_H * 2);
    unsigned short* xb   = (unsigned short*)alloc((size_t)N_NODES * D_IN * 2);  // 51.2 MB
    unsigned short* H1   = (unsigned short*)alloc((size_t)N_NODES * D_H * 2);   // 51.2 MB
    unsigned short* out1 = (unsigned short*)alloc((size_t)N_NODES * D_H * 2);   // 51.2 MB
    unsigned short* H2   = (unsigned short*)alloc((size_t)N_NODES * D_OUT * 2); // 25.6 MB

    // CSR build + norms
    k_zero<<<(N_NODES + 255) / 256, 256, 0, stream>>>(indeg, N_NODES);
    k_indeg<<<(N_EDGES + 255) / 256, 256, 0, stream>>>(dst, indeg);
    k_partials<<<NB, 256, 0, stream>>>(indeg, bsum);
    k_scanb<<<1, 256, 0, stream>>>(bsum, boff);
    k_finalize<<<NB, 256, 0, stream>>>(indeg, boff, row_start, cursor, dinv);
    k_bucket<<<(N_EDGES + 255) / 256, 256, 0, stream>>>(src, dst, cursor, csr_src);

    // input conversion + weight transposes
    {
        const long long n8 = (long long)N_NODES * D_IN / 8;
        k_cvt<<<(int)((n8 + 255) / 256), 256, 0, stream>>>(x, xb, n8);
        dim3 b(32, 8);
        dim3 g1(D_IN / 32, D_H / 32);
        k_wt<<<g1, b, 0, stream>>>(W1, W1t, D_IN, D_H);
        dim3 g2(D_H / 32, D_OUT / 32);
        k_wt<<<g2, b, 0, stream>>>(W2, W2t, D_H, D_OUT);
    }

    const int nrb = (N_NODES + 127) / 128;  // 391
    const int rgrp = (nrb + 7) / 8;         // 49
    const int nbpc = (N_NODES + 31) / 32;   // 1563 blocks per column chunk

    // ----- layer 1 -----
    {
        const int ncb = D_H / 128;          // 4
        k_gemm<<<8 * ncb * rgrp, 256, 0, stream>>>(xb, W1t, H1, N_NODES, D_H, D_IN, ncb, nrb);
    }
    k_agg_chunk<512, true, 2><<<8 * 2 * nbpc, 256, 0, stream>>>(
        H1, b1, out1, row_start, csr_src, dinv, nbpc);

    // ----- layer 2 -----
    {
        const int ncb = D_OUT / 128;        // 2
        k_gemm<<<8 * ncb * rgrp, 256, 0, stream>>>(out1, W2t, H2, N_NODES, D_OUT, D_H, ncb, nrb);
    }
    k_agg_chunk<256, false, 1><<<8 * 1 * nbpc, 256, 0, stream>>>(
        H2, b2, out, row_start, csr_src, dinv, nbpc);
}

// Round 11
// 284.030 us; speedup vs baseline: 1.2817x; 1.2817x over previous
//
#include <hip/hip_runtime.h>
#include <math.h>

#define N_NODES 50000
#define N_EDGES 500000
#define D_IN 512
#define D_H  512
#define D_OUT 256
#define NB 196  // ceil(N_NODES/256)

typedef __attribute__((ext_vector_type(8))) short bf16x8;
typedef __attribute__((ext_vector_type(8))) unsigned short ushort8;
typedef __attribute__((ext_vector_type(4))) float f32x4;

__device__ __forceinline__ float b2f(unsigned short u) {
    union { unsigned int i; float f; } v; v.i = ((unsigned int)u) << 16; return v.f;
}
__device__ __forceinline__ unsigned short f2b(float f) {
    unsigned int x = __float_as_uint(f);
    unsigned int r = (x + 0x7fffu + ((x >> 16) & 1u)) >> 16;  // RNE
    return (unsigned short)r;
}

// ---------------- fused prep: zero(indeg) + cvt(x->bf16) + wt(W1) + wt(W2) ------
// Block-range partitioned; independent work overlaps instead of serializing.

#define ZB   196                        // ceil(N_NODES/256): zero region
#define CB   12500                      // (N_NODES*D_IN/8)/256: cvt region
#define W1B  256                        // (D_IN/32)*(D_H/32)
#define W2B  128                        // (D_H/32)*(D_OUT/32)

__global__ __launch_bounds__(256) void k_prep(const float* __restrict__ x,
                                              unsigned short* __restrict__ xb,
                                              const float* __restrict__ W1,
                                              unsigned short* __restrict__ W1t,
                                              const float* __restrict__ W2,
                                              unsigned short* __restrict__ W2t,
                                              int* __restrict__ indeg) {
    __shared__ float t[32][33];
    const int b = blockIdx.x;
    const int tid = threadIdx.x;

    if (b < ZB) {
        const int i = b * 256 + tid;
        if (i < N_NODES) indeg[i] = 0;
        return;
    }
    if (b < ZB + CB) {
        const long long i = (long long)(b - ZB) * 256 + tid;  // ushort8 units
        float4 v0 = ((const float4*)x)[i * 2];
        float4 v1 = ((const float4*)x)[i * 2 + 1];
        ushort8 o;
        o[0] = f2b(v0.x); o[1] = f2b(v0.y); o[2] = f2b(v0.z); o[3] = f2b(v0.w);
        o[4] = f2b(v1.x); o[5] = f2b(v1.y); o[6] = f2b(v1.z); o[7] = f2b(v1.w);
        ((ushort8*)xb)[i] = o;
        return;
    }
    // weight transpose regions: W [K][N] fp32 -> Wt [N][K] bf16, 32x32 tiles
    const float* W;
    unsigned short* Wt;
    int K, N, idx;
    if (b < ZB + CB + W1B) {
        W = W1; Wt = W1t; K = D_IN; N = D_H; idx = b - (ZB + CB);
    } else {
        W = W2; Wt = W2t; K = D_H; N = D_OUT; idx = b - (ZB + CB + W1B);
    }
    const int nkb = K / 32;
    const int bk = (idx % nkb) * 32;
    const int bn = (idx / nkb) * 32;
    const int tx = tid & 31, ty = tid >> 5;  // (32,8)
    for (int i = ty; i < 32; i += 8) t[i][tx] = W[(size_t)(bk + i) * N + bn + tx];
    __syncthreads();
    for (int i = ty; i < 32; i += 8)
        Wt[(size_t)(bn + i) * K + bk + tx] = f2b(t[tx][i]);
}

// ---------------- degree / CSR build ----------------

__global__ __launch_bounds__(256) void k_indeg(const int* __restrict__ dst,
                                               int* __restrict__ indeg) {
    int i = blockIdx.x * 256 + threadIdx.x;
    if (i < N_EDGES) atomicAdd(&indeg[dst[i]], 1);
}

__global__ __launch_bounds__(256) void k_partials(const int* __restrict__ indeg,
                                                  int* __restrict__ bsum) {
    __shared__ int wsum[4];
    const int tid = threadIdx.x, lane = tid & 63, w = tid >> 6;
    const int i = blockIdx.x * 256 + tid;
    int v = (i < N_NODES) ? indeg[i] : 0;
#pragma unroll
    for (int o = 32; o > 0; o >>= 1) v += __shfl_down(v, o, 64);
    if (lane == 0) wsum[w] = v;
    __syncthreads();
    if (tid == 0) bsum[blockIdx.x] = wsum[0] + wsum[1] + wsum[2] + wsum[3];
}

__global__ __launch_bounds__(256) void k_scanb(const int* __restrict__ bsum,
                                               int* __restrict__ boff) {
    __shared__ int wsum[4];
    const int tid = threadIdx.x, lane = tid & 63, w = tid >> 6;
    const int v = (tid < NB) ? bsum[tid] : 0;
    int s = v;
#pragma unroll
    for (int o = 1; o < 64; o <<= 1) {
        int t = __shfl_up(s, o, 64);
        if (lane >= o) s += t;
    }
    if (lane == 63) wsum[w] = s;
    __syncthreads();
    int add = 0;
    for (int k = 0; k < w; ++k) add += wsum[k];
    if (tid < NB) boff[tid] = add + s - v;
}

__global__ __launch_bounds__(256) void k_finalize(const int* __restrict__ indeg,
                                                  const int* __restrict__ boff,
                                                  int* __restrict__ row_start,
                                                  int* __restrict__ cursor,
                                                  float* __restrict__ dinv) {
    __shared__ int wsum[4];
    const int tid = threadIdx.x, lane = tid & 63, w = tid >> 6;
    const int i = blockIdx.x * 256 + tid;
    const int v = (i < N_NODES) ? indeg[i] : 0;
    int s = v;
#pragma unroll
    for (int o = 1; o < 64; o <<= 1) {
        int t = __shfl_up(s, o, 64);
        if (lane >= o) s += t;
    }
    if (lane == 63) wsum[w] = s;
    __syncthreads();
    int add = boff[blockIdx.x];
    for (int k = 0; k < w; ++k) add += wsum[k];
    if (i < N_NODES) {
        const int excl = add + s - v;
        row_start[i] = excl;
        cursor[i] = excl;
        dinv[i] = rsqrtf((float)(1 + v));
    }
    if (i == N_NODES) row_start[N_NODES] = N_EDGES;
}

__global__ __launch_bounds__(256) void k_bucket(const int* __restrict__ src,
                                                const int* __restrict__ dst,
                                                int* __restrict__ cursor,
                                                int* __restrict__ csr_src) {
    int e = blockIdx.x * 256 + threadIdx.x;
    if (e >= N_EDGES) return;
    int pos = atomicAdd(&cursor[dst[e]], 1);
    csr_src[pos] = src[e];
}

// ---------------- 128x128 bf16 GEMM, BK=64, dbuf, swizzled LDS, vec epilogue ----
// (R9 structure, unchanged: 0 bank conflicts, vectorized dwordx4 C stores.)

__device__ __forceinline__ void gload16(const void* g, void* l) {
    __builtin_amdgcn_global_load_lds(
        (const __attribute__((address_space(1))) unsigned int*)g,
        (__attribute__((address_space(3))) unsigned int*)l, 16, 0, 0);
}

__global__ __launch_bounds__(256, 2) void k_gemm(const unsigned short* __restrict__ A,
                                                 const unsigned short* __restrict__ Bt,
                                                 unsigned short* __restrict__ C,
                                                 int M, int N, int K,
                                                 int ncb, int nrb) {
    __shared__ __align__(16) short As[2][128 * 64];
    __shared__ __align__(16) short Bs[2][128 * 64];

    const int bid = blockIdx.x;
    const int xcd = bid & 7;
    const int sidx = bid >> 3;
    const int cb = sidx % ncb;
    const int rb = (sidx / ncb) * 8 + xcd;
    if (rb >= nrb) return;
    const int brow = rb * 128;
    const int bcol = cb * 128;

    const int tid = threadIdx.x;
    const int wid = tid >> 6;
    const int lane = tid & 63;
    const int wr = wid >> 1, wc = wid & 1;
    const int lhi = lane >> 4, llo = lane & 15;

    f32x4 acc[4][4];
#pragma unroll
    for (int i = 0; i < 4; ++i)
#pragma unroll
        for (int j = 0; j < 4; ++j) acc[i][j] = (f32x4){0.f, 0.f, 0.f, 0.f};

#define STAGE(buf, kt)                                                          \
    {                                                                           \
        _Pragma("unroll") for (int g = 0; g < 4; ++g) {                         \
            const int s = g * 256 + tid;                                        \
            const int row = s >> 3;                                             \
            const int sc = (s & 7) ^ (row & 7);                                 \
            int gr = brow + row; gr = gr < M ? gr : M - 1;                      \
            gload16(A + (size_t)gr * K + (kt) + sc * 8,                         \
                    &As[buf][(g * 256 + wid * 64) * 8]);                        \
            gload16(Bt + (size_t)(bcol + row) * K + (kt) + sc * 8,              \
                    &Bs[buf][(g * 256 + wid * 64) * 8]);                        \
        }                                                                       \
    }

    const int nt = K / 64;

    STAGE(0, 0);
    __syncthreads();

    int cur = 0;
    for (int t = 0; t < nt; ++t) {
        if (t + 1 < nt) STAGE(cur ^ 1, (t + 1) * 64);

#pragma unroll
        for (int ks = 0; ks < 2; ++ks) {
            bf16x8 af[4], bf[4];
#pragma unroll
            for (int mi = 0; mi < 4; ++mi) {
                const int row = wr * 64 + mi * 16 + llo;
                af[mi] = *(const bf16x8*)&As[cur][row * 64 + (((ks * 4 + lhi) ^ (llo & 7)) * 8)];
            }
#pragma unroll
            for (int ni = 0; ni < 4; ++ni) {
                const int row = wc * 64 + ni * 16 + llo;
                bf[ni] = *(const bf16x8*)&Bs[cur][row * 64 + (((ks * 4 + lhi) ^ (llo & 7)) * 8)];
            }
#pragma unroll
            for (int mi = 0; mi < 4; ++mi)
#pragma unroll
                for (int ni = 0; ni < 4; ++ni)
                    acc[mi][ni] = __builtin_amdgcn_mfma_f32_16x16x32_bf16(
                        af[mi], bf[ni], acc[mi][ni], 0, 0, 0);
        }

        __syncthreads();
        cur ^= 1;
    }
#undef STAGE

    // epilogue: per-wave 64x64 swizzled LDS tile -> dwordx4 stores
    short* cws = &As[0][0] + wid * 4096;

#pragma unroll
    for (int mi = 0; mi < 4; ++mi)
#pragma unroll
        for (int ni = 0; ni < 4; ++ni) {
            const f32x4 v = acc[mi][ni];
#pragma unroll
            for (int r = 0; r < 4; ++r) {
                const int row = mi * 16 + lhi * 4 + r;
                const int col = ni * 16 + llo;
                const int chunk = (col >> 3) ^ (row & 7);
                cws[row * 64 + chunk * 8 + (col & 7)] = (short)f2b(v[r]);
            }
        }
    __syncthreads();

    {
        const int rsub = lane >> 3;
        const int c = lane & 7;
#pragma unroll
        for (int i = 0; i < 8; ++i) {
            const int row = i * 8 + rsub;
            const ushort8 o = *(const ushort8*)&cws[row * 64 + ((c ^ (row & 7)) * 8)];
            const int grow = brow + wr * 64 + row;
            if (grow < M)
                *(ushort8*)(C + (size_t)grow * N + bcol + wc * 64 + c * 8) = o;
        }
    }
}

// ---------------- fused aggregate: self + gather + bias + ELU (R9 version) ------

template <int D, bool BF16_OUT>
__global__ __launch_bounds__(256) void k_aggregate(const unsigned short* __restrict__ H,
                                                   const float* __restrict__ bias,
                                                   void* __restrict__ outv,
                                                   const int* __restrict__ row_start,
                                                   const int* __restrict__ csr_src,
                                                   const float* __restrict__ dinv) {
    const int wid = threadIdx.x >> 6;
    const int lane = threadIdx.x & 63;
    int n, c0;
    if (D == 512) { n = blockIdx.x * 4 + wid; c0 = lane * 8; }
    else          { n = blockIdx.x * 8 + wid * 2 + (lane >> 5); c0 = (lane & 31) * 8; }
    if (n >= N_NODES) return;

    const float di = dinv[n];
    float acc[8];
    {
        const float ws = di * di;
        ushort8 v = *(const ushort8*)(H + (size_t)n * D + c0);
#pragma unroll
        for (int e = 0; e < 8; ++e) acc[e] = b2f(v[e]) * ws;
    }

    const int e0 = row_start[n];
    const int e1 = row_start[n + 1];
    int j = e0;
    for (; j + 8 <= e1; j += 8) {
        int s[8];
        float wgt[8];
#pragma unroll
        for (int q = 0; q < 8; ++q) s[q] = csr_src[j + q];
#pragma unroll
        for (int q = 0; q < 8; ++q) wgt[q] = dinv[s[q]] * di;
#pragma unroll
        for (int h = 0; h < 2; ++h) {
            const ushort8 v0 = *(const ushort8*)(H + (size_t)s[h * 4 + 0] * D + c0);
            const ushort8 v1 = *(const ushort8*)(H + (size_t)s[h * 4 + 1] * D + c0);
            const ushort8 v2 = *(const ushort8*)(H + (size_t)s[h * 4 + 2] * D + c0);
            const ushort8 v3 = *(const ushort8*)(H + (size_t)s[h * 4 + 3] * D + c0);
#pragma unroll
            for (int e = 0; e < 8; ++e) {
                acc[e] = fmaf(b2f(v0[e]), wgt[h * 4 + 0], acc[e]);
                acc[e] = fmaf(b2f(v1[e]), wgt[h * 4 + 1], acc[e]);
                acc[e] = fmaf(b2f(v2[e]), wgt[h * 4 + 2], acc[e]);
                acc[e] = fmaf(b2f(v3[e]), wgt[h * 4 + 3], acc[e]);
            }
        }
    }
    for (; j + 4 <= e1; j += 4) {
        const int s0 = csr_src[j + 0];
        const int s1 = csr_src[j + 1];
        const int s2 = csr_src[j + 2];
        const int s3 = csr_src[j + 3];
        const float w0 = dinv[s0] * di;
        const float w1 = dinv[s1] * di;
        const float w2 = dinv[s2] * di;
        const float w3 = dinv[s3] * di;
        const ushort8 v0 = *(const ushort8*)(H + (size_t)s0 * D + c0);
        const ushort8 v1 = *(const ushort8*)(H + (size_t)s1 * D + c0);
        const ushort8 v2 = *(const ushort8*)(H + (size_t)s2 * D + c0);
        const ushort8 v3 = *(const ushort8*)(H + (size_t)s3 * D + c0);
#pragma unroll
        for (int e = 0; e < 8; ++e) {
            acc[e] = fmaf(b2f(v0[e]), w0, acc[e]);
            acc[e] = fmaf(b2f(v1[e]), w1, acc[e]);
            acc[e] = fmaf(b2f(v2[e]), w2, acc[e]);
            acc[e] = fmaf(b2f(v3[e]), w3, acc[e]);
        }
    }
    for (; j < e1; ++j) {
        const int s = csr_src[j];
        const float ws = dinv[s] * di;
        const ushort8 v = *(const ushort8*)(H + (size_t)s * D + c0);
#pragma unroll
        for (int e = 0; e < 8; ++e) acc[e] = fmaf(b2f(v[e]), ws, acc[e]);
    }

#pragma unroll
    for (int e = 0; e < 8; ++e) {
        float t = acc[e] + bias[c0 + e];
        acc[e] = t > 0.f ? t : expf(t) - 1.f;
    }

    if (BF16_OUT) {
        ushort8 o;
#pragma unroll
        for (int e = 0; e < 8; ++e) o[e] = f2b(acc[e]);
        *(ushort8*)((unsigned short*)outv + (size_t)n * D + c0) = o;
    } else {
        float* orow = (float*)outv + (size_t)n * D + c0;
        *(float4*)orow = make_float4(acc[0], acc[1], acc[2], acc[3]);
        *(float4*)(orow + 4) = make_float4(acc[4], acc[5], acc[6], acc[7]);
    }
}

// ---------------- launch ----------------

extern "C" void kernel_launch(void* const* d_in, const int* in_sizes, int n_in,
                              void* d_out, int out_size, void* d_ws, size_t ws_size,
                              hipStream_t stream) {
    const float* x  = (const float*)d_in[0];
    const int* ei   = (const int*)d_in[1];
    const int* src  = ei;
    const int* dst  = ei + N_EDGES;
    const float* W1 = (const float*)d_in[2];
    const float* b1 = (const float*)d_in[3];
    const float* W2 = (const float*)d_in[4];
    const float* b2 = (const float*)d_in[5];
    float* out = (float*)d_out;

    char* ws = (char*)d_ws;
    size_t off = 0;
    auto alloc = [&](size_t bytes) -> void* {
        void* p = ws + off;
        off = (off + bytes + 255) & ~(size_t)255;
        return p;
    };
    int*   indeg     = (int*)alloc((size_t)N_NODES * 4);
    int*   bsum      = (int*)alloc((size_t)NB * 4);
    int*   boff      = (int*)alloc((size_t)NB * 4);
    int*   row_start = (int*)alloc((size_t)(N_NODES + 1) * 4);
    int*   cursor    = (int*)alloc((size_t)N_NODES * 4);
    int*   csr_src   = (int*)alloc((size_t)N_EDGES * 4);
    float* dinv      = (float*)alloc((size_t)N_NODES * 4);
    unsigned short* W1t  = (unsigned short*)alloc((size_t)D_H * D_IN * 2);
    unsigned short* W2t  = (unsigned short*)alloc((size_t)D_OUT * D_H * 2);
    unsigned short* xb   = (unsigned short*)alloc((size_t)N_NODES * D_IN * 2);  // 51.2 MB
    unsigned short* H1   = (unsigned short*)alloc((size_t)N_NODES * D_H * 2);   // 51.2 MB
    unsigned short* out1 = (unsigned short*)alloc((size_t)N_NODES * D_H * 2);   // 51.2 MB
    unsigned short* H2   = (unsigned short*)alloc((size_t)N_NODES * D_OUT * 2); // 25.6 MB

    // fused prep: zero(indeg) + x->bf16 + both weight transposes
    k_prep<<<ZB + CB + W1B + W2B, 256, 0, stream>>>(x, xb, W1, W1t, W2, W2t, indeg);

    // CSR build + norms
    k_indeg<<<(N_EDGES + 255) / 256, 256, 0, stream>>>(dst, indeg);
    k_partials<<<NB, 256, 0, stream>>>(indeg, bsum);
    k_scanb<<<1, 256, 0, stream>>>(bsum, boff);
    k_finalize<<<NB, 256, 0, stream>>>(indeg, boff, row_start, cursor, dinv);
    k_bucket<<<(N_EDGES + 255) / 256, 256, 0, stream>>>(src, dst, cursor, csr_src);

    const int nrb = (N_NODES + 127) / 128;  // 391
    const int rgrp = (nrb + 7) / 8;         // 49

    // ----- layer 1 -----
    {
        const int ncb = D_H / 128;          // 4
        k_gemm<<<8 * ncb * rgrp, 256, 0, stream>>>(xb, W1t, H1, N_NODES, D_H, D_IN, ncb, nrb);
    }
    k_aggregate<512, true><<<(N_NODES + 3) / 4, 256, 0, stream>>>(H1, b1, out1, row_start, csr_src, dinv);

    // ----- layer 2 -----
    {
        const int ncb = D_OUT / 128;        // 2
        k_gemm<<<8 * ncb * rgrp, 256, 0, stream>>>(out1, W2t, H2, N_NODES, D_OUT, D_H, ncb, nrb);
    }
    k_aggregate<256, false><<<(N_NODES + 7) / 8, 256, 0, stream>>>(H2, b2, out, row_start, csr_src, dinv);
}

// Round 12
// 275.100 us; speedup vs baseline: 1.3234x; 1.0325x over previous
//
#include <hip/hip_runtime.h>
#include <math.h>

#define N_NODES 50000
#define N_EDGES 500000
#define D_IN 512
#define D_H  512
#define D_OUT 256
#define NB 196    // ceil(N_NODES/256)
#define NBK 1954  // ceil(N_EDGES/256)

typedef __attribute__((ext_vector_type(8))) short bf16x8;
typedef __attribute__((ext_vector_type(8))) unsigned short ushort8;
typedef __attribute__((ext_vector_type(4))) float f32x4;

__device__ __forceinline__ float b2f(unsigned short u) {
    union { unsigned int i; float f; } v; v.i = ((unsigned int)u) << 16; return v.f;
}
__device__ __forceinline__ unsigned short f2b(float f) {
    unsigned int x = __float_as_uint(f);
    unsigned int r = (x + 0x7fffu + ((x >> 16) & 1u)) >> 16;  // RNE
    return (unsigned short)r;
}

// ---------------- zero (must precede indeg atomics) ----------------

__global__ __launch_bounds__(256) void k_zero(int* __restrict__ p, int n) {
    int i = blockIdx.x * 256 + threadIdx.x;
    if (i < n) p[i] = 0;
}

// ---------------- fused prep: indeg-hist + cvt(x->bf16) + wt(W1) + wt(W2) -------
// Block-range partitioned; the atomic histogram hides under the BW-bound cvt.

#define CB   12500                      // (N_NODES*D_IN/8)/256: cvt region
#define W1B  256                        // (D_IN/32)*(D_H/32)
#define W2B  128                        // (D_H/32)*(D_OUT/32)

__global__ __launch_bounds__(256) void k_prep(const float* __restrict__ x,
                                              unsigned short* __restrict__ xb,
                                              const float* __restrict__ W1,
                                              unsigned short* __restrict__ W1t,
                                              const float* __restrict__ W2,
                                              unsigned short* __restrict__ W2t,
                                              const int* __restrict__ dst,
                                              int* __restrict__ indeg) {
    __shared__ float t[32][33];
    int b = blockIdx.x;
    const int tid = threadIdx.x;

    if (b < NBK) {  // in-degree histogram
        const int e = b * 256 + tid;
        if (e < N_EDGES) atomicAdd(&indeg[dst[e]], 1);
        return;
    }
    b -= NBK;
    if (b < CB) {   // x fp32 -> bf16
        const long long i = (long long)b * 256 + tid;  // ushort8 units
        float4 v0 = ((const float4*)x)[i * 2];
        float4 v1 = ((const float4*)x)[i * 2 + 1];
        ushort8 o;
        o[0] = f2b(v0.x); o[1] = f2b(v0.y); o[2] = f2b(v0.z); o[3] = f2b(v0.w);
        o[4] = f2b(v1.x); o[5] = f2b(v1.y); o[6] = f2b(v1.z); o[7] = f2b(v1.w);
        ((ushort8*)xb)[i] = o;
        return;
    }
    b -= CB;
    // weight transpose: W [K][N] fp32 -> Wt [N][K] bf16, 32x32 tiles
    const float* W;
    unsigned short* Wt;
    int K, N, idx;
    if (b < W1B) { W = W1; Wt = W1t; K = D_IN; N = D_H; idx = b; }
    else         { W = W2; Wt = W2t; K = D_H; N = D_OUT; idx = b - W1B; }
    const int nkb = K / 32;
    const int bk = (idx % nkb) * 32;
    const int bn = (idx / nkb) * 32;
    const int tx = tid & 31, ty = tid >> 5;  // (32,8)
    for (int i = ty; i < 32; i += 8) t[i][tx] = W[(size_t)(bk + i) * N + bn + tx];
    __syncthreads();
    for (int i = ty; i < 32; i += 8)
        Wt[(size_t)(bn + i) * K + bk + tx] = f2b(t[tx][i]);
}

// ---------------- CSR scan chain ----------------

__global__ __launch_bounds__(256) void k_partials(const int* __restrict__ indeg,
                                                  int* __restrict__ bsum) {
    __shared__ int wsum[4];
    const int tid = threadIdx.x, lane = tid & 63, w = tid >> 6;
    const int i = blockIdx.x * 256 + tid;
    int v = (i < N_NODES) ? indeg[i] : 0;
#pragma unroll
    for (int o = 32; o > 0; o >>= 1) v += __shfl_down(v, o, 64);
    if (lane == 0) wsum[w] = v;
    __syncthreads();
    if (tid == 0) bsum[blockIdx.x] = wsum[0] + wsum[1] + wsum[2] + wsum[3];
}

__global__ __launch_bounds__(256) void k_scanb(const int* __restrict__ bsum,
                                               int* __restrict__ boff) {
    __shared__ int wsum[4];
    const int tid = threadIdx.x, lane = tid & 63, w = tid >> 6;
    const int v = (tid < NB) ? bsum[tid] : 0;
    int s = v;
#pragma unroll
    for (int o = 1; o < 64; o <<= 1) {
        int t = __shfl_up(s, o, 64);
        if (lane >= o) s += t;
    }
    if (lane == 63) wsum[w] = s;
    __syncthreads();
    int add = 0;
    for (int k = 0; k < w; ++k) add += wsum[k];
    if (tid < NB) boff[tid] = add + s - v;
}

__global__ __launch_bounds__(256) void k_finalize(const int* __restrict__ indeg,
                                                  const int* __restrict__ boff,
                                                  int* __restrict__ row_start,
                                                  int* __restrict__ cursor,
                                                  float* __restrict__ dinv) {
    __shared__ int wsum[4];
    const int tid = threadIdx.x, lane = tid & 63, w = tid >> 6;
    const int i = blockIdx.x * 256 + tid;
    const int v = (i < N_NODES) ? indeg[i] : 0;
    int s = v;
#pragma unroll
    for (int o = 1; o < 64; o <<= 1) {
        int t = __shfl_up(s, o, 64);
        if (lane >= o) s += t;
    }
    if (lane == 63) wsum[w] = s;
    __syncthreads();
    int add = boff[blockIdx.x];
    for (int k = 0; k < w; ++k) add += wsum[k];
    if (i < N_NODES) {
        const int excl = add + s - v;
        row_start[i] = excl;
        cursor[i] = excl;
        dinv[i] = rsqrtf((float)(1 + v));
    }
    if (i == N_NODES) row_start[N_NODES] = N_EDGES;
}

// ---------------- 128x128 bf16 GEMM, BK=64, dbuf, swizzled LDS, vec epilogue ----
// C'[r,:] = rowscale[r] * (A @ Bt^T)[r,:]  (dinv pre-scale fused in epilogue).
// Optional fused bucket region (blocks [0,nbk)): CSR bucketing, independent work.

__device__ __forceinline__ void gload16(const void* g, void* l) {
    __builtin_amdgcn_global_load_lds(
        (const __attribute__((address_space(1))) unsigned int*)g,
        (__attribute__((address_space(3))) unsigned int*)l, 16, 0, 0);
}

template <bool FUSE_BUCKET>
__global__ __launch_bounds__(256, 2) void k_gemm(const unsigned short* __restrict__ A,
                                                 const unsigned short* __restrict__ Bt,
                                                 unsigned short* __restrict__ C,
                                                 const float* __restrict__ rowscale,
                                                 int M, int N, int K,
                                                 int ncb, int nrb,
                                                 const int* __restrict__ src,
                                                 const int* __restrict__ dst,
                                                 int* __restrict__ cursor,
                                                 int* __restrict__ csr_src) {
    __shared__ __align__(16) short As[2][128 * 64];
    __shared__ __align__(16) short Bs[2][128 * 64];

    if (FUSE_BUCKET && blockIdx.x < NBK) {
        const int e = blockIdx.x * 256 + threadIdx.x;
        if (e < N_EDGES) {
            const int pos = atomicAdd(&cursor[dst[e]], 1);
            csr_src[pos] = src[e];
        }
        return;
    }
    const int bid = blockIdx.x - (FUSE_BUCKET ? NBK : 0);
    const int xcd = bid & 7;
    const int sidx = bid >> 3;
    const int cb = sidx % ncb;
    const int rb = (sidx / ncb) * 8 + xcd;
    if (rb >= nrb) return;
    const int brow = rb * 128;
    const int bcol = cb * 128;

    const int tid = threadIdx.x;
    const int wid = tid >> 6;
    const int lane = tid & 63;
    const int wr = wid >> 1, wc = wid & 1;
    const int lhi = lane >> 4, llo = lane & 15;

    f32x4 acc[4][4];
#pragma unroll
    for (int i = 0; i < 4; ++i)
#pragma unroll
        for (int j = 0; j < 4; ++j) acc[i][j] = (f32x4){0.f, 0.f, 0.f, 0.f};

#define STAGE(buf, kt)                                                          \
    {                                                                           \
        _Pragma("unroll") for (int g = 0; g < 4; ++g) {                         \
            const int s = g * 256 + tid;                                        \
            const int row = s >> 3;                                             \
            const int sc = (s & 7) ^ (row & 7);                                 \
            int gr = brow + row; gr = gr < M ? gr : M - 1;                      \
            gload16(A + (size_t)gr * K + (kt) + sc * 8,                         \
                    &As[buf][(g * 256 + wid * 64) * 8]);                        \
            gload16(Bt + (size_t)(bcol + row) * K + (kt) + sc * 8,              \
                    &Bs[buf][(g * 256 + wid * 64) * 8]);                        \
        }                                                                       \
    }

    const int nt = K / 64;

    STAGE(0, 0);
    __syncthreads();

    int cur = 0;
    for (int t = 0; t < nt; ++t) {
        if (t + 1 < nt) STAGE(cur ^ 1, (t + 1) * 64);

#pragma unroll
        for (int ks = 0; ks < 2; ++ks) {
            bf16x8 af[4], bf[4];
#pragma unroll
            for (int mi = 0; mi < 4; ++mi) {
                const int row = wr * 64 + mi * 16 + llo;
                af[mi] = *(const bf16x8*)&As[cur][row * 64 + (((ks * 4 + lhi) ^ (llo & 7)) * 8)];
            }
#pragma unroll
            for (int ni = 0; ni < 4; ++ni) {
                const int row = wc * 64 + ni * 16 + llo;
                bf[ni] = *(const bf16x8*)&Bs[cur][row * 64 + (((ks * 4 + lhi) ^ (llo & 7)) * 8)];
            }
#pragma unroll
            for (int mi = 0; mi < 4; ++mi)
#pragma unroll
                for (int ni = 0; ni < 4; ++ni)
                    acc[mi][ni] = __builtin_amdgcn_mfma_f32_16x16x32_bf16(
                        af[mi], bf[ni], acc[mi][ni], 0, 0, 0);
        }

        __syncthreads();
        cur ^= 1;
    }
#undef STAGE

    // epilogue: rowscale, per-wave 64x64 swizzled LDS tile, dwordx4 stores
    short* cws = &As[0][0] + wid * 4096;

#pragma unroll
    for (int mi = 0; mi < 4; ++mi) {
#pragma unroll
        for (int r = 0; r < 4; ++r) {
            const int lrow = mi * 16 + lhi * 4 + r;
            int grow = brow + wr * 64 + lrow;
            grow = grow < M ? grow : M - 1;
            const float ds = rowscale[grow];
#pragma unroll
            for (int ni = 0; ni < 4; ++ni) {
                const int col = ni * 16 + llo;
                const int chunk = (col >> 3) ^ (lrow & 7);
                cws[lrow * 64 + chunk * 8 + (col & 7)] = (short)f2b(acc[mi][ni][r] * ds);
            }
        }
    }
    __syncthreads();

    {
        const int rsub = lane >> 3;
        const int c = lane & 7;
#pragma unroll
        for (int i = 0; i < 8; ++i) {
            const int row = i * 8 + rsub;
            const ushort8 o = *(const ushort8*)&cws[row * 64 + ((c ^ (row & 7)) * 8)];
            const int grow = brow + wr * 64 + row;
            if (grow < M)
                *(ushort8*)(C + (size_t)grow * N + bcol + wc * 64 + c * 8) = o;
        }
    }
}

// ---------------- fused aggregate on pre-scaled H': sum + dinv[d] + bias + ELU ---
// H' is bf16 with dinv[row] pre-applied: out[n] = ELU(dinv[n]*(H'[n] + sum H'[src]) + b)
// Inner loop is pure add — no per-edge weight load/FMA.

template <int D, bool BF16_OUT>
__global__ __launch_bounds__(256) void k_aggregate(const unsigned short* __restrict__ H,
                                                   const float* __restrict__ bias,
                                                   void* __restrict__ outv,
                                                   const int* __restrict__ row_start,
                                                   const int* __restrict__ csr_src,
                                                   const float* __restrict__ dinv) {
    const int wid = threadIdx.x >> 6;
    const int lane = threadIdx.x & 63;
    int n, c0;
    if (D == 512) { n = blockIdx.x * 4 + wid; c0 = lane * 8; }
    else          { n = blockIdx.x * 8 + wid * 2 + (lane >> 5); c0 = (lane & 31) * 8; }
    if (n >= N_NODES) return;

    float acc[8];
    {
        ushort8 v = *(const ushort8*)(H + (size_t)n * D + c0);
#pragma unroll
        for (int e = 0; e < 8; ++e) acc[e] = b2f(v[e]);
    }

    const int e0 = row_start[n];
    const int e1 = row_start[n + 1];
    int j = e0;
    for (; j + 8 <= e1; j += 8) {
        int s[8];
#pragma unroll
        for (int q = 0; q < 8; ++q) s[q] = csr_src[j + q];
#pragma unroll
        for (int h = 0; h < 2; ++h) {
            const ushort8 v0 = *(const ushort8*)(H + (size_t)s[h * 4 + 0] * D + c0);
            const ushort8 v1 = *(const ushort8*)(H + (size_t)s[h * 4 + 1] * D + c0);
            const ushort8 v2 = *(const ushort8*)(H + (size_t)s[h * 4 + 2] * D + c0);
            const ushort8 v3 = *(const ushort8*)(H + (size_t)s[h * 4 + 3] * D + c0);
#pragma unroll
            for (int e = 0; e < 8; ++e) {
                acc[e] += b2f(v0[e]);
                acc[e] += b2f(v1[e]);
                acc[e] += b2f(v2[e]);
                acc[e] += b2f(v3[e]);
            }
        }
    }
    for (; j + 4 <= e1; j += 4) {
        const int s0 = csr_src[j + 0];
        const int s1 = csr_src[j + 1];
        const int s2 = csr_src[j + 2];
        const int s3 = csr_src[j + 3];
        const ushort8 v0 = *(const ushort8*)(H + (size_t)s0 * D + c0);
        const ushort8 v1 = *(const ushort8*)(H + (size_t)s1 * D + c0);
        const ushort8 v2 = *(const ushort8*)(H + (size_t)s2 * D + c0);
        const ushort8 v3 = *(const ushort8*)(H + (size_t)s3 * D + c0);
#pragma unroll
        for (int e = 0; e < 8; ++e) {
            acc[e] += b2f(v0[e]);
            acc[e] += b2f(v1[e]);
            acc[e] += b2f(v2[e]);
            acc[e] += b2f(v3[e]);
        }
    }
    for (; j < e1; ++j) {
        const int s = csr_src[j];
        const ushort8 v = *(const ushort8*)(H + (size_t)s * D + c0);
#pragma unroll
        for (int e = 0; e < 8; ++e) acc[e] += b2f(v[e]);
    }

    const float di = dinv[n];
#pragma unroll
    for (int e = 0; e < 8; ++e) {
        float t = fmaf(acc[e], di, bias[c0 + e]);
        acc[e] = t > 0.f ? t : expf(t) - 1.f;
    }

    if (BF16_OUT) {
        ushort8 o;
#pragma unroll
        for (int e = 0; e < 8; ++e) o[e] = f2b(acc[e]);
        *(ushort8*)((unsigned short*)outv + (size_t)n * D + c0) = o;
    } else {
        float* orow = (float*)outv + (size_t)n * D + c0;
        *(float4*)orow = make_float4(acc[0], acc[1], acc[2], acc[3]);
        *(float4*)(orow + 4) = make_float4(acc[4], acc[5], acc[6], acc[7]);
    }
}

// ---------------- launch ----------------

extern "C" void kernel_launch(void* const* d_in, const int* in_sizes, int n_in,
                              void* d_out, int out_size, void* d_ws, size_t ws_size,
                              hipStream_t stream) {
    const float* x  = (const float*)d_in[0];
    const int* ei   = (const int*)d_in[1];
    const int* src  = ei;
    const int* dst  = ei + N_EDGES;
    const float* W1 = (const float*)d_in[2];
    const float* b1 = (const float*)d_in[3];
    const float* W2 = (const float*)d_in[4];
    const float* b2 = (const float*)d_in[5];
    float* out = (float*)d_out;

    char* ws = (char*)d_ws;
    size_t off = 0;
    auto alloc = [&](size_t bytes) -> void* {
        void* p = ws + off;
        off = (off + bytes + 255) & ~(size_t)255;
        return p;
    };
    int*   indeg     = (int*)alloc((size_t)N_NODES * 4);
    int*   bsum      = (int*)alloc((size_t)NB * 4);
    int*   boff      = (int*)alloc((size_t)NB * 4);
    int*   row_start = (int*)alloc((size_t)(N_NODES + 1) * 4);
    int*   cursor    = (int*)alloc((size_t)N_NODES * 4);
    int*   csr_src   = (int*)alloc((size_t)N_EDGES * 4);
    float* dinv      = (float*)alloc((size_t)N_NODES * 4);
    unsigned short* W1t  = (unsigned short*)alloc((size_t)D_H * D_IN * 2);
    unsigned short* W2t  = (unsigned short*)alloc((size_t)D_OUT * D_H * 2);
    unsigned short* xb   = (unsigned short*)alloc((size_t)N_NODES * D_IN * 2);  // 51.2 MB
    unsigned short* H1   = (unsigned short*)alloc((size_t)N_NODES * D_H * 2);   // 51.2 MB
    unsigned short* out1 = (unsigned short*)alloc((size_t)N_NODES * D_H * 2);   // 51.2 MB
    unsigned short* H2   = (unsigned short*)alloc((size_t)N_NODES * D_OUT * 2); // 25.6 MB

    // L0: zero indeg (must precede atomics)
    k_zero<<<NB, 256, 0, stream>>>(indeg, N_NODES);
    // L1: fused indeg-hist + cvt + weight transposes
    k_prep<<<NBK + CB + W1B + W2B, 256, 0, stream>>>(x, xb, W1, W1t, W2, W2t, dst, indeg);
    // L2-4: scan chain -> row_start/cursor/dinv
    k_partials<<<NB, 256, 0, stream>>>(indeg, bsum);
    k_scanb<<<1, 256, 0, stream>>>(bsum, boff);
    k_finalize<<<NB, 256, 0, stream>>>(indeg, boff, row_start, cursor, dinv);

    const int nrb = (N_NODES + 127) / 128;  // 391
    const int rgrp = (nrb + 7) / 8;         // 49

    // ----- layer 1 (bucket fused into GEMM1 launch) -----
    {
        const int ncb = D_H / 128;          // 4
        k_gemm<true><<<NBK + 8 * ncb * rgrp, 256, 0, stream>>>(
            xb, W1t, H1, dinv, N_NODES, D_H, D_IN, ncb, nrb, src, dst, cursor, csr_src);
    }
    k_aggregate<512, true><<<(N_NODES + 3) / 4, 256, 0, stream>>>(H1, b1, out1, row_start, csr_src, dinv);

    // ----- layer 2 -----
    {
        const int ncb = D_OUT / 128;        // 2
        k_gemm<false><<<8 * ncb * rgrp, 256, 0, stream>>>(
            out1, W2t, H2, dinv, N_NODES, D_OUT, D_H, ncb, nrb, nullptr, nullptr, nullptr, nullptr);
    }
    k_aggregate<256, false><<<(N_NODES + 7) / 8, 256, 0, stream>>>(H2, b2, out, row_start, csr_src, dinv);
}

// Round 13
// 272.847 us; speedup vs baseline: 1.3343x; 1.0083x over previous
//
#include <hip/hip_runtime.h>
#include <math.h>

#define N_NODES 50000
#define N_EDGES 500000
#define D_IN 512
#define D_H  512
#define D_OUT 256
#define NB 196    // ceil(N_NODES/256)
#define NBK 1954  // ceil(N_EDGES/256)

typedef __attribute__((ext_vector_type(8))) short bf16x8;
typedef __attribute__((ext_vector_type(8))) unsigned short ushort8;
typedef __attribute__((ext_vector_type(4))) float f32x4;

__device__ __forceinline__ float b2f(unsigned short u) {
    union { unsigned int i; float f; } v; v.i = ((unsigned int)u) << 16; return v.f;
}
__device__ __forceinline__ unsigned short f2b(float f) {
    unsigned int x = __float_as_uint(f);
    unsigned int r = (x + 0x7fffu + ((x >> 16) & 1u)) >> 16;  // RNE
    return (unsigned short)r;
}

// ---------------- zero (must precede indeg atomics) ----------------

__global__ __launch_bounds__(256) void k_zero(int* __restrict__ p, int n) {
    int i = blockIdx.x * 256 + threadIdx.x;
    if (i < n) p[i] = 0;
}

// ---------------- fused prep: indeg-hist + cvt(x->bf16) + wt(W1) + wt(W2) -------

#define CB   12500                      // (N_NODES*D_IN/8)/256: cvt region
#define W1B  256                        // (D_IN/32)*(D_H/32)
#define W2B  128                        // (D_H/32)*(D_OUT/32)

__global__ __launch_bounds__(256) void k_prep(const float* __restrict__ x,
                                              unsigned short* __restrict__ xb,
                                              const float* __restrict__ W1,
                                              unsigned short* __restrict__ W1t,
                                              const float* __restrict__ W2,
                                              unsigned short* __restrict__ W2t,
                                              const int* __restrict__ dst,
                                              int* __restrict__ indeg) {
    __shared__ float t[32][33];
    int b = blockIdx.x;
    const int tid = threadIdx.x;

    if (b < NBK) {  // in-degree histogram
        const int e = b * 256 + tid;
        if (e < N_EDGES) atomicAdd(&indeg[dst[e]], 1);
        return;
    }
    b -= NBK;
    if (b < CB) {   // x fp32 -> bf16
        const long long i = (long long)b * 256 + tid;  // ushort8 units
        float4 v0 = ((const float4*)x)[i * 2];
        float4 v1 = ((const float4*)x)[i * 2 + 1];
        ushort8 o;
        o[0] = f2b(v0.x); o[1] = f2b(v0.y); o[2] = f2b(v0.z); o[3] = f2b(v0.w);
        o[4] = f2b(v1.x); o[5] = f2b(v1.y); o[6] = f2b(v1.z); o[7] = f2b(v1.w);
        ((ushort8*)xb)[i] = o;
        return;
    }
    b -= CB;
    // weight transpose: W [K][N] fp32 -> Wt [N][K] bf16, 32x32 tiles
    const float* W;
    unsigned short* Wt;
    int K, N, idx;
    if (b < W1B) { W = W1; Wt = W1t; K = D_IN; N = D_H; idx = b; }
    else         { W = W2; Wt = W2t; K = D_H; N = D_OUT; idx = b - W1B; }
    const int nkb = K / 32;
    const int bk = (idx % nkb) * 32;
    const int bn = (idx / nkb) * 32;
    const int tx = tid & 31, ty = tid >> 5;  // (32,8)
    for (int i = ty; i < 32; i += 8) t[i][tx] = W[(size_t)(bk + i) * N + bn + tx];
    __syncthreads();
    for (int i = ty; i < 32; i += 8)
        Wt[(size_t)(bn + i) * K + bk + tx] = f2b(t[tx][i]);
}

// ---------------- CSR scan chain ----------------

__global__ __launch_bounds__(256) void k_partials(const int* __restrict__ indeg,
                                                  int* __restrict__ bsum) {
    __shared__ int wsum[4];
    const int tid = threadIdx.x, lane = tid & 63, w = tid >> 6;
    const int i = blockIdx.x * 256 + tid;
    int v = (i < N_NODES) ? indeg[i] : 0;
#pragma unroll
    for (int o = 32; o > 0; o >>= 1) v += __shfl_down(v, o, 64);
    if (lane == 0) wsum[w] = v;
    __syncthreads();
    if (tid == 0) bsum[blockIdx.x] = wsum[0] + wsum[1] + wsum[2] + wsum[3];
}

__global__ __launch_bounds__(256) void k_scanb(const int* __restrict__ bsum,
                                               int* __restrict__ boff) {
    __shared__ int wsum[4];
    const int tid = threadIdx.x, lane = tid & 63, w = tid >> 6;
    const int v = (tid < NB) ? bsum[tid] : 0;
    int s = v;
#pragma unroll
    for (int o = 1; o < 64; o <<= 1) {
        int t = __shfl_up(s, o, 64);
        if (lane >= o) s += t;
    }
    if (lane == 63) wsum[w] = s;
    __syncthreads();
    int add = 0;
    for (int k = 0; k < w; ++k) add += wsum[k];
    if (tid < NB) boff[tid] = add + s - v;
}

__global__ __launch_bounds__(256) void k_finalize(const int* __restrict__ indeg,
                                                  const int* __restrict__ boff,
                                                  int* __restrict__ row_start,
                                                  int* __restrict__ cursor,
                                                  float* __restrict__ dinv) {
    __shared__ int wsum[4];
    const int tid = threadIdx.x, lane = tid & 63, w = tid >> 6;
    const int i = blockIdx.x * 256 + tid;
    const int v = (i < N_NODES) ? indeg[i] : 0;
    int s = v;
#pragma unroll
    for (int o = 1; o < 64; o <<= 1) {
        int t = __shfl_up(s, o, 64);
        if (lane >= o) s += t;
    }
    if (lane == 63) wsum[w] = s;
    __syncthreads();
    int add = boff[blockIdx.x];
    for (int k = 0; k < w; ++k) add += wsum[k];
    if (i < N_NODES) {
        const int excl = add + s - v;
        row_start[i] = excl;
        cursor[i] = excl;
        dinv[i] = rsqrtf((float)(1 + v));
    }
    if (i == N_NODES) row_start[N_NODES] = N_EDGES;
}

// ---------------- 128x128 bf16 GEMM, BK=32, DOUBLE-buffered, 32 KB LDS ----------
// C'[r,:] = rowscale[r] * (A @ Bt^T)[r,:].  4 waves 2x2; per-wave 64x64.
// 32 KB LDS -> 4 blocks/CU (vs 64 KB/2 blocks in R8-R12: the m97-vs-m132
// occupancy lesson). XOR swizzle: chunk ^= row&3, involution pre-applied on
// gload SOURCE and on the ds_read side. Epilogue reuses the same 32 KB for
// per-wave 64x64 C tiles -> dwordx4 stores. Optional fused bucket region.

__device__ __forceinline__ void gload16(const void* g, void* l) {
    __builtin_amdgcn_global_load_lds(
        (const __attribute__((address_space(1))) unsigned int*)g,
        (__attribute__((address_space(3))) unsigned int*)l, 16, 0, 0);
}

template <bool FUSE_BUCKET>
__global__ __launch_bounds__(256, 4) void k_gemm(const unsigned short* __restrict__ A,
                                                 const unsigned short* __restrict__ Bt,
                                                 unsigned short* __restrict__ C,
                                                 const float* __restrict__ rowscale,
                                                 int M, int N, int K,
                                                 int ncb, int nrb,
                                                 const int* __restrict__ src,
                                                 const int* __restrict__ dst,
                                                 int* __restrict__ cursor,
                                                 int* __restrict__ csr_src) {
    // carve: A bufs [0,4096),[4096,8192); B bufs [8192,12288),[12288,16384) shorts
    __shared__ __align__(16) short lds[16384];

    if (FUSE_BUCKET && blockIdx.x < NBK) {
        const int e = blockIdx.x * 256 + threadIdx.x;
        if (e < N_EDGES) {
            const int pos = atomicAdd(&cursor[dst[e]], 1);
            csr_src[pos] = src[e];
        }
        return;
    }
    const int bid = blockIdx.x - (FUSE_BUCKET ? NBK : 0);
    const int xcd = bid & 7;
    const int sidx = bid >> 3;
    const int cb = sidx % ncb;
    const int rb = (sidx / ncb) * 8 + xcd;
    if (rb >= nrb) return;
    const int brow = rb * 128;
    const int bcol = cb * 128;

    const int tid = threadIdx.x;
    const int wid = tid >> 6;
    const int lane = tid & 63;
    const int wr = wid >> 1, wc = wid & 1;
    const int lhi = lane >> 4, llo = lane & 15;

    f32x4 acc[4][4];
#pragma unroll
    for (int i = 0; i < 4; ++i)
#pragma unroll
        for (int j = 0; j < 4; ++j) acc[i][j] = (f32x4){0.f, 0.f, 0.f, 0.f};

    // staging: slot s = g*256 + tid (g<2); row = s>>2; pos = s&3; src chunk = pos^(row&3)
#define STAGE(buf, kt)                                                          \
    {                                                                           \
        _Pragma("unroll") for (int g = 0; g < 2; ++g) {                         \
            const int s = g * 256 + tid;                                        \
            const int row = s >> 2;                                             \
            const int sc = (s & 3) ^ (row & 3);                                 \
            int gr = brow + row; gr = gr < M ? gr : M - 1;                      \
            gload16(A + (size_t)gr * K + (kt) + sc * 8,                         \
                    &lds[(buf) * 4096 + (g * 256 + wid * 64) * 8]);             \
            gload16(Bt + (size_t)(bcol + row) * K + (kt) + sc * 8,              \
                    &lds[8192 + (buf) * 4096 + (g * 256 + wid * 64) * 8]);      \
        }                                                                       \
    }

    const int nt = K / 32;  // 16

    STAGE(0, 0);
    __syncthreads();

    int cur = 0;
    for (int t = 0; t < nt; ++t) {
        if (t + 1 < nt) STAGE(cur ^ 1, (t + 1) * 32);

        bf16x8 af[4], bf[4];
#pragma unroll
        for (int mi = 0; mi < 4; ++mi) {
            const int row = wr * 64 + mi * 16 + llo;
            af[mi] = *(const bf16x8*)&lds[cur * 4096 + row * 32 + ((lhi ^ (row & 3)) * 8)];
        }
#pragma unroll
        for (int ni = 0; ni < 4; ++ni) {
            const int row = wc * 64 + ni * 16 + llo;
            bf[ni] = *(const bf16x8*)&lds[8192 + cur * 4096 + row * 32 + ((lhi ^ (row & 3)) * 8)];
        }
#pragma unroll
        for (int mi = 0; mi < 4; ++mi)
#pragma unroll
            for (int ni = 0; ni < 4; ++ni)
                acc[mi][ni] = __builtin_amdgcn_mfma_f32_16x16x32_bf16(
                    af[mi], bf[ni], acc[mi][ni], 0, 0, 0);

        __syncthreads();
        cur ^= 1;
    }
#undef STAGE

    // epilogue: rowscale, per-wave 64x64 swizzled LDS tile, dwordx4 stores
    short* cws = &lds[wid * 4096];  // [64 rows][8 chunks of 8], chunk ^= (row&7)

#pragma unroll
    for (int mi = 0; mi < 4; ++mi) {
#pragma unroll
        for (int r = 0; r < 4; ++r) {
            const int lrow = mi * 16 + lhi * 4 + r;
            int grow = brow + wr * 64 + lrow;
            grow = grow < M ? grow : M - 1;
            const float ds = rowscale[grow];
#pragma unroll
            for (int ni = 0; ni < 4; ++ni) {
                const int col = ni * 16 + llo;
                const int chunk = (col >> 3) ^ (lrow & 7);
                cws[lrow * 64 + chunk * 8 + (col & 7)] = (short)f2b(acc[mi][ni][r] * ds);
            }
        }
    }
    __syncthreads();

    {
        const int rsub = lane >> 3;
        const int c = lane & 7;
#pragma unroll
        for (int i = 0; i < 8; ++i) {
            const int row = i * 8 + rsub;
            const ushort8 o = *(const ushort8*)&cws[row * 64 + ((c ^ (row & 7)) * 8)];
            const int grow = brow + wr * 64 + row;
            if (grow < M)
                *(ushort8*)(C + (size_t)grow * N + bcol + wc * 64 + c * 8) = o;
        }
    }
}

// ---------------- fused aggregate on pre-scaled H': sum + dinv[d] + bias + ELU ---

template <int D, bool BF16_OUT>
__global__ __launch_bounds__(256) void k_aggregate(const unsigned short* __restrict__ H,
                                                   const float* __restrict__ bias,
                                                   void* __restrict__ outv,
                                                   const int* __restrict__ row_start,
                                                   const int* __restrict__ csr_src,
                                                   const float* __restrict__ dinv) {
    const int wid = threadIdx.x >> 6;
    const int lane = threadIdx.x & 63;
    int n, c0;
    if (D == 512) { n = blockIdx.x * 4 + wid; c0 = lane * 8; }
    else          { n = blockIdx.x * 8 + wid * 2 + (lane >> 5); c0 = (lane & 31) * 8; }
    if (n >= N_NODES) return;

    float acc[8];
    {
        ushort8 v = *(const ushort8*)(H + (size_t)n * D + c0);
#pragma unroll
        for (int e = 0; e < 8; ++e) acc[e] = b2f(v[e]);
    }

    const int e0 = row_start[n];
    const int e1 = row_start[n + 1];
    int j = e0;
    for (; j + 8 <= e1; j += 8) {
        int s[8];
#pragma unroll
        for (int q = 0; q < 8; ++q) s[q] = csr_src[j + q];
#pragma unroll
        for (int h = 0; h < 2; ++h) {
            const ushort8 v0 = *(const ushort8*)(H + (size_t)s[h * 4 + 0] * D + c0);
            const ushort8 v1 = *(const ushort8*)(H + (size_t)s[h * 4 + 1] * D + c0);
            const ushort8 v2 = *(const ushort8*)(H + (size_t)s[h * 4 + 2] * D + c0);
            const ushort8 v3 = *(const ushort8*)(H + (size_t)s[h * 4 + 3] * D + c0);
#pragma unroll
            for (int e = 0; e < 8; ++e) {
                acc[e] += b2f(v0[e]);
                acc[e] += b2f(v1[e]);
                acc[e] += b2f(v2[e]);
                acc[e] += b2f(v3[e]);
            }
        }
    }
    for (; j + 4 <= e1; j += 4) {
        const int s0 = csr_src[j + 0];
        const int s1 = csr_src[j + 1];
        const int s2 = csr_src[j + 2];
        const int s3 = csr_src[j + 3];
        const ushort8 v0 = *(const ushort8*)(H + (size_t)s0 * D + c0);
        const ushort8 v1 = *(const ushort8*)(H + (size_t)s1 * D + c0);
        const ushort8 v2 = *(const ushort8*)(H + (size_t)s2 * D + c0);
        const ushort8 v3 = *(const ushort8*)(H + (size_t)s3 * D + c0);
#pragma unroll
        for (int e = 0; e < 8; ++e) {
            acc[e] += b2f(v0[e]);
            acc[e] += b2f(v1[e]);
            acc[e] += b2f(v2[e]);
            acc[e] += b2f(v3[e]);
        }
    }
    for (; j < e1; ++j) {
        const int s = csr_src[j];
        const ushort8 v = *(const ushort8*)(H + (size_t)s * D + c0);
#pragma unroll
        for (int e = 0; e < 8; ++e) acc[e] += b2f(v[e]);
    }

    const float di = dinv[n];
#pragma unroll
    for (int e = 0; e < 8; ++e) {
        float t = fmaf(acc[e], di, bias[c0 + e]);
        acc[e] = t > 0.f ? t : expf(t) - 1.f;
    }

    if (BF16_OUT) {
        ushort8 o;
#pragma unroll
        for (int e = 0; e < 8; ++e) o[e] = f2b(acc[e]);
        *(ushort8*)((unsigned short*)outv + (size_t)n * D + c0) = o;
    } else {
        float* orow = (float*)outv + (size_t)n * D + c0;
        *(float4*)orow = make_float4(acc[0], acc[1], acc[2], acc[3]);
        *(float4*)(orow + 4) = make_float4(acc[4], acc[5], acc[6], acc[7]);
    }
}

// ---------------- launch ----------------

extern "C" void kernel_launch(void* const* d_in, const int* in_sizes, int n_in,
                              void* d_out, int out_size, void* d_ws, size_t ws_size,
                              hipStream_t stream) {
    const float* x  = (const float*)d_in[0];
    const int* ei   = (const int*)d_in[1];
    const int* src  = ei;
    const int* dst  = ei + N_EDGES;
    const float* W1 = (const float*)d_in[2];
    const float* b1 = (const float*)d_in[3];
    const float* W2 = (const float*)d_in[4];
    const float* b2 = (const float*)d_in[5];
    float* out = (float*)d_out;

    char* ws = (char*)d_ws;
    size_t off = 0;
    auto alloc = [&](size_t bytes) -> void* {
        void* p = ws + off;
        off = (off + bytes + 255) & ~(size_t)255;
        return p;
    };
    int*   indeg     = (int*)alloc((size_t)N_NODES * 4);
    int*   bsum      = (int*)alloc((size_t)NB * 4);
    int*   boff      = (int*)alloc((size_t)NB * 4);
    int*   row_start = (int*)alloc((size_t)(N_NODES + 1) * 4);
    int*   cursor    = (int*)alloc((size_t)N_NODES * 4);
    int*   csr_src   = (int*)alloc((size_t)N_EDGES * 4);
    float* dinv      = (float*)alloc((size_t)N_NODES * 4);
    unsigned short* W1t  = (unsigned short*)alloc((size_t)D_H * D_IN * 2);
    unsigned short* W2t  = (unsigned short*)alloc((size_t)D_OUT * D_H * 2);
    unsigned short* xb   = (unsigned short*)alloc((size_t)N_NODES * D_IN * 2);  // 51.2 MB
    unsigned short* H1   = (unsigned short*)alloc((size_t)N_NODES * D_H * 2);   // 51.2 MB
    unsigned short* out1 = (unsigned short*)alloc((size_t)N_NODES * D_H * 2);   // 51.2 MB
    unsigned short* H2   = (unsigned short*)alloc((size_t)N_NODES * D_OUT * 2); // 25.6 MB

    // L0: zero indeg (must precede atomics)
    k_zero<<<NB, 256, 0, stream>>>(indeg, N_NODES);
    // L1: fused indeg-hist + cvt + weight transposes
    k_prep<<<NBK + CB + W1B + W2B, 256, 0, stream>>>(x, xb, W1, W1t, W2, W2t, dst, indeg);
    // L2-4: scan chain -> row_start/cursor/dinv
    k_partials<<<NB, 256, 0, stream>>>(indeg, bsum);
    k_scanb<<<1, 256, 0, stream>>>(bsum, boff);
    k_finalize<<<NB, 256, 0, stream>>>(indeg, boff, row_start, cursor, dinv);

    const int nrb = (N_NODES + 127) / 128;  // 391
    const int rgrp = (nrb + 7) / 8;         // 49

    // ----- layer 1 (bucket fused into GEMM1 launch) -----
    {
        const int ncb = D_H / 128;          // 4
        k_gemm<true><<<NBK + 8 * ncb * rgrp, 256, 0, stream>>>(
            xb, W1t, H1, dinv, N_NODES, D_H, D_IN, ncb, nrb, src, dst, cursor, csr_src);
    }
    k_aggregate<512, true><<<(N_NODES + 3) / 4, 256, 0, stream>>>(H1, b1, out1, row_start, csr_src, dinv);

    // ----- layer 2 -----
    {
        const int ncb = D_OUT / 128;        // 2
        k_gemm<false><<<8 * ncb * rgrp, 256, 0, stream>>>(
            out1, W2t, H2, dinv, N_NODES, D_OUT, D_H, ncb, nrb, nullptr, nullptr, nullptr, nullptr);
    }
    k_aggregate<256, false><<<(N_NODES + 7) / 8, 256, 0, stream>>>(H2, b2, out, row_start, csr_src, dinv);
}

// Round 14
// 270.435 us; speedup vs baseline: 1.3462x; 1.0089x over previous
//
#include <hip/hip_runtime.h>
#include <math.h>

#define N_NODES 50000
#define N_EDGES 500000
#define D_IN 512
#define D_H  512
#define D_OUT 256
#define NB 196    // ceil(N_NODES/256)
#define NBK 1954  // ceil(N_EDGES/256)

typedef __attribute__((ext_vector_type(8))) short bf16x8;
typedef __attribute__((ext_vector_type(8))) unsigned short ushort8;
typedef __attribute__((ext_vector_type(4))) float f32x4;

__device__ __forceinline__ float b2f(unsigned short u) {
    union { unsigned int i; float f; } v; v.i = ((unsigned int)u) << 16; return v.f;
}
__device__ __forceinline__ unsigned short f2b(float f) {
    unsigned int x = __float_as_uint(f);
    unsigned int r = (x + 0x7fffu + ((x >> 16) & 1u)) >> 16;  // RNE
    return (unsigned short)r;
}

// ---------------- zero (must precede indeg atomics) ----------------

__global__ __launch_bounds__(256) void k_zero(int* __restrict__ p, int n) {
    int i = blockIdx.x * 256 + threadIdx.x;
    if (i < n) p[i] = 0;
}

// ---------------- fused prep: indeg-hist + wt(W1) + wt(W2) ----------------
// (x->bf16 cvt REMOVED: GEMM1 now reads x fp32 directly and converts in-kernel.)

#define W1B  256                        // (D_IN/32)*(D_H/32)
#define W2B  128                        // (D_H/32)*(D_OUT/32)

__global__ __launch_bounds__(256) void k_prep(const float* __restrict__ W1,
                                              unsigned short* __restrict__ W1t,
                                              const float* __restrict__ W2,
                                              unsigned short* __restrict__ W2t,
                                              const int* __restrict__ dst,
                                              int* __restrict__ indeg) {
    __shared__ float t[32][33];
    int b = blockIdx.x;
    const int tid = threadIdx.x;

    if (b < NBK) {  // in-degree histogram
        const int e = b * 256 + tid;
        if (e < N_EDGES) atomicAdd(&indeg[dst[e]], 1);
        return;
    }
    b -= NBK;
    // weight transpose: W [K][N] fp32 -> Wt [N][K] bf16, 32x32 tiles
    const float* W;
    unsigned short* Wt;
    int K, N, idx;
    if (b < W1B) { W = W1; Wt = W1t; K = D_IN; N = D_H; idx = b; }
    else         { W = W2; Wt = W2t; K = D_H; N = D_OUT; idx = b - W1B; }
    const int nkb = K / 32;
    const int bk = (idx % nkb) * 32;
    const int bn = (idx / nkb) * 32;
    const int tx = tid & 31, ty = tid >> 5;  // (32,8)
    for (int i = ty; i < 32; i += 8) t[i][tx] = W[(size_t)(bk + i) * N + bn + tx];
    __syncthreads();
    for (int i = ty; i < 32; i += 8)
        Wt[(size_t)(bn + i) * K + bk + tx] = f2b(t[tx][i]);
}

// ---------------- CSR scan chain ----------------

__global__ __launch_bounds__(256) void k_partials(const int* __restrict__ indeg,
                                                  int* __restrict__ bsum) {
    __shared__ int wsum[4];
    const int tid = threadIdx.x, lane = tid & 63, w = tid >> 6;
    const int i = blockIdx.x * 256 + tid;
    int v = (i < N_NODES) ? indeg[i] : 0;
#pragma unroll
    for (int o = 32; o > 0; o >>= 1) v += __shfl_down(v, o, 64);
    if (lane == 0) wsum[w] = v;
    __syncthreads();
    if (tid == 0) bsum[blockIdx.x] = wsum[0] + wsum[1] + wsum[2] + wsum[3];
}

__global__ __launch_bounds__(256) void k_scanb(const int* __restrict__ bsum,
                                               int* __restrict__ boff) {
    __shared__ int wsum[4];
    const int tid = threadIdx.x, lane = tid & 63, w = tid >> 6;
    const int v = (tid < NB) ? bsum[tid] : 0;
    int s = v;
#pragma unroll
    for (int o = 1; o < 64; o <<= 1) {
        int t = __shfl_up(s, o, 64);
        if (lane >= o) s += t;
    }
    if (lane == 63) wsum[w] = s;
    __syncthreads();
    int add = 0;
    for (int k = 0; k < w; ++k) add += wsum[k];
    if (tid < NB) boff[tid] = add + s - v;
}

__global__ __launch_bounds__(256) void k_finalize(const int* __restrict__ indeg,
                                                  const int* __restrict__ boff,
                                                  int* __restrict__ row_start,
                                                  int* __restrict__ cursor,
                                                  float* __restrict__ dinv) {
    __shared__ int wsum[4];
    const int tid = threadIdx.x, lane = tid & 63, w = tid >> 6;
    const int i = blockIdx.x * 256 + tid;
    const int v = (i < N_NODES) ? indeg[i] : 0;
    int s = v;
#pragma unroll
    for (int o = 1; o < 64; o <<= 1) {
        int t = __shfl_up(s, o, 64);
        if (lane >= o) s += t;
    }
    if (lane == 63) wsum[w] = s;
    __syncthreads();
    int add = boff[blockIdx.x];
    for (int k = 0; k < w; ++k) add += wsum[k];
    if (i < N_NODES) {
        const int excl = add + s - v;
        row_start[i] = excl;
        cursor[i] = excl;
        dinv[i] = rsqrtf((float)(1 + v));
    }
    if (i == N_NODES) row_start[N_NODES] = N_EDGES;
}

// ---------------- 128x128 bf16 GEMM, BK=32, dbuf, 32 KB LDS, 4 blocks/CU -------
// C'[r,:] = rowscale[r] * (A @ Bt^T)[r,:].  4 waves 2x2; per-wave 64x64.
// A32: A read as fp32 (x directly), reg-staged issue-early / cvt+ds_write late.
// XOR swizzle chunk^=(row&3) (involution on gload source / ds_write slot and
// on the ds_read side). Epilogue: rowscale + per-wave 64x64 swizzled LDS tile
// -> dwordx4 stores. Optional fused bucket region.

__device__ __forceinline__ void gload16(const void* g, void* l) {
    __builtin_amdgcn_global_load_lds(
        (const __attribute__((address_space(1))) unsigned int*)g,
        (__attribute__((address_space(3))) unsigned int*)l, 16, 0, 0);
}

template <bool A32, bool FUSE_BUCKET>
__global__ __launch_bounds__(256, 4) void k_gemm(const void* __restrict__ Av,
                                                 const unsigned short* __restrict__ Bt,
                                                 unsigned short* __restrict__ C,
                                                 const float* __restrict__ rowscale,
                                                 int M, int N, int K,
                                                 int ncb, int nrb,
                                                 const int* __restrict__ src,
                                                 const int* __restrict__ dst,
                                                 int* __restrict__ cursor,
                                                 int* __restrict__ csr_src) {
    // carve: A bufs [0,4096),[4096,8192); B bufs [8192,12288),[12288,16384) shorts
    __shared__ __align__(16) short lds[16384];

    if (FUSE_BUCKET && blockIdx.x < NBK) {
        const int e = blockIdx.x * 256 + threadIdx.x;
        if (e < N_EDGES) {
            const int pos = atomicAdd(&cursor[dst[e]], 1);
            csr_src[pos] = src[e];
        }
        return;
    }
    const int bid = blockIdx.x - (FUSE_BUCKET ? NBK : 0);
    const int xcd = bid & 7;
    const int sidx = bid >> 3;
    const int cb = sidx % ncb;
    const int rb = (sidx / ncb) * 8 + xcd;
    if (rb >= nrb) return;
    const int brow = rb * 128;
    const int bcol = cb * 128;

    const int tid = threadIdx.x;
    const int wid = tid >> 6;
    const int lane = tid & 63;
    const int wr = wid >> 1, wc = wid & 1;
    const int lhi = lane >> 4, llo = lane & 15;

    const float* Af = (const float*)Av;
    const unsigned short* Ab = (const unsigned short*)Av;

    f32x4 acc[4][4];
#pragma unroll
    for (int i = 0; i < 4; ++i)
#pragma unroll
        for (int j = 0; j < 4; ++j) acc[i][j] = (f32x4){0.f, 0.f, 0.f, 0.f};

    // slot geometry (BK=32): s = g*256+tid (g<2); row = s>>2; pos = s&3;
    // source chunk sc = pos ^ (row&3); each chunk = 8 bf16 (or 8 floats for A32).
    float4 ar[2][2];  // A32 reg staging, static-indexed

#define STAGE_A16(buf, kt)                                                      \
    {                                                                           \
        _Pragma("unroll") for (int g = 0; g < 2; ++g) {                         \
            const int s = g * 256 + tid;                                        \
            const int row = s >> 2;                                             \
            const int sc = (s & 3) ^ (row & 3);                                 \
            int gr = brow + row; gr = gr < M ? gr : M - 1;                      \
            gload16(Ab + (size_t)gr * K + (kt) + sc * 8,                        \
                    &lds[(buf) * 4096 + (g * 256 + wid * 64) * 8]);             \
        }                                                                       \
    }
#define STAGE_B(buf, kt)                                                        \
    {                                                                           \
        _Pragma("unroll") for (int g = 0; g < 2; ++g) {                         \
            const int s = g * 256 + tid;                                        \
            const int row = s >> 2;                                             \
            const int sc = (s & 3) ^ (row & 3);                                 \
            gload16(Bt + (size_t)(bcol + row) * K + (kt) + sc * 8,              \
                    &lds[8192 + (buf) * 4096 + (g * 256 + wid * 64) * 8]);      \
        }                                                                       \
    }
#define LOAD_A32(kt)                                                            \
    {                                                                           \
        _Pragma("unroll") for (int g = 0; g < 2; ++g) {                         \
            const int s = g * 256 + tid;                                        \
            const int row = s >> 2;                                             \
            const int sc = (s & 3) ^ (row & 3);                                 \
            int gr = brow + row; gr = gr < M ? gr : M - 1;                      \
            const float* p = Af + (size_t)gr * K + (kt) + sc * 8;               \
            ar[g][0] = *(const float4*)p;                                       \
            ar[g][1] = *(const float4*)(p + 4);                                 \
        }                                                                       \
    }
#define WRITE_A32(buf)                                                          \
    {                                                                           \
        _Pragma("unroll") for (int g = 0; g < 2; ++g) {                         \
            ushort8 u;                                                          \
            u[0] = f2b(ar[g][0].x); u[1] = f2b(ar[g][0].y);                     \
            u[2] = f2b(ar[g][0].z); u[3] = f2b(ar[g][0].w);                     \
            u[4] = f2b(ar[g][1].x); u[5] = f2b(ar[g][1].y);                     \
            u[6] = f2b(ar[g][1].z); u[7] = f2b(ar[g][1].w);                     \
            *(ushort8*)&lds[(buf) * 4096 + (g * 256 + tid) * 8] = u;            \
        }                                                                       \
    }

    const int nt = K / 32;  // 16

    // prologue: tile 0 -> buf 0
    if (A32) {
        LOAD_A32(0);
        STAGE_B(0, 0);
        WRITE_A32(0);
    } else {
        STAGE_A16(0, 0);
        STAGE_B(0, 0);
    }
    __syncthreads();

    int cur = 0;
    for (int t = 0; t < nt; ++t) {
        const bool more = (t + 1 < nt);
        if (more) {
            if (A32) {
                LOAD_A32((t + 1) * 32);   // issue-early; cvt+ds_write after MFMAs
            } else {
                STAGE_A16(cur ^ 1, (t + 1) * 32);
            }
            STAGE_B(cur ^ 1, (t + 1) * 32);
        }

        bf16x8 af[4], bf[4];
#pragma unroll
        for (int mi = 0; mi < 4; ++mi) {
            const int row = wr * 64 + mi * 16 + llo;
            af[mi] = *(const bf16x8*)&lds[cur * 4096 + row * 32 + ((lhi ^ (row & 3)) * 8)];
        }
#pragma unroll
        for (int ni = 0; ni < 4; ++ni) {
            const int row = wc * 64 + ni * 16 + llo;
            bf[ni] = *(const bf16x8*)&lds[8192 + cur * 4096 + row * 32 + ((lhi ^ (row & 3)) * 8)];
        }
#pragma unroll
        for (int mi = 0; mi < 4; ++mi)
#pragma unroll
            for (int ni = 0; ni < 4; ++ni)
                acc[mi][ni] = __builtin_amdgcn_mfma_f32_16x16x32_bf16(
                    af[mi], bf[ni], acc[mi][ni], 0, 0, 0);

        if (A32 && more) WRITE_A32(cur ^ 1);

        __syncthreads();
        cur ^= 1;
    }
#undef STAGE_A16
#undef STAGE_B
#undef LOAD_A32
#undef WRITE_A32

    // epilogue: rowscale, per-wave 64x64 swizzled LDS tile, dwordx4 stores
    short* cws = &lds[wid * 4096];  // [64 rows][8 chunks of 8], chunk ^= (row&7)

#pragma unroll
    for (int mi = 0; mi < 4; ++mi) {
#pragma unroll
        for (int r = 0; r < 4; ++r) {
            const int lrow = mi * 16 + lhi * 4 + r;
            int grow = brow + wr * 64 + lrow;
            grow = grow < M ? grow : M - 1;
            const float ds = rowscale[grow];
#pragma unroll
            for (int ni = 0; ni < 4; ++ni) {
                const int col = ni * 16 + llo;
                const int chunk = (col >> 3) ^ (lrow & 7);
                cws[lrow * 64 + chunk * 8 + (col & 7)] = (short)f2b(acc[mi][ni][r] * ds);
            }
        }
    }
    __syncthreads();

    {
        const int rsub = lane >> 3;
        const int c = lane & 7;
#pragma unroll
        for (int i = 0; i < 8; ++i) {
            const int row = i * 8 + rsub;
            const ushort8 o = *(const ushort8*)&cws[row * 64 + ((c ^ (row & 7)) * 8)];
            const int grow = brow + wr * 64 + row;
            if (grow < M)
                *(ushort8*)(C + (size_t)grow * N + bcol + wc * 64 + c * 8) = o;
        }
    }
}

// ---------------- fused aggregate on pre-scaled H': sum + dinv[d] + bias + ELU ---

template <int D, bool BF16_OUT>
__global__ __launch_bounds__(256) void k_aggregate(const unsigned short* __restrict__ H,
                                                   const float* __restrict__ bias,
                                                   void* __restrict__ outv,
                                                   const int* __restrict__ row_start,
                                                   const int* __restrict__ csr_src,
                                                   const float* __restrict__ dinv) {
    const int wid = threadIdx.x >> 6;
    const int lane = threadIdx.x & 63;
    int n, c0;
    if (D == 512) { n = blockIdx.x * 4 + wid; c0 = lane * 8; }
    else          { n = blockIdx.x * 8 + wid * 2 + (lane >> 5); c0 = (lane & 31) * 8; }
    if (n >= N_NODES) return;

    float acc[8];
    {
        ushort8 v = *(const ushort8*)(H + (size_t)n * D + c0);
#pragma unroll
        for (int e = 0; e < 8; ++e) acc[e] = b2f(v[e]);
    }

    const int e0 = row_start[n];
    const int e1 = row_start[n + 1];
    int j = e0;
    for (; j + 8 <= e1; j += 8) {
        int s[8];
#pragma unroll
        for (int q = 0; q < 8; ++q) s[q] = csr_src[j + q];
#pragma unroll
        for (int h = 0; h < 2; ++h) {
            const ushort8 v0 = *(const ushort8*)(H + (size_t)s[h * 4 + 0] * D + c0);
            const ushort8 v1 = *(const ushort8*)(H + (size_t)s[h * 4 + 1] * D + c0);
            const ushort8 v2 = *(const ushort8*)(H + (size_t)s[h * 4 + 2] * D + c0);
            const ushort8 v3 = *(const ushort8*)(H + (size_t)s[h * 4 + 3] * D + c0);
#pragma unroll
            for (int e = 0; e < 8; ++e) {
                acc[e] += b2f(v0[e]);
                acc[e] += b2f(v1[e]);
                acc[e] += b2f(v2[e]);
                acc[e] += b2f(v3[e]);
            }
        }
    }
    for (; j + 4 <= e1; j += 4) {
        const int s0 = csr_src[j + 0];
        const int s1 = csr_src[j + 1];
        const int s2 = csr_src[j + 2];
        const int s3 = csr_src[j + 3];
        const ushort8 v0 = *(const ushort8*)(H + (size_t)s0 * D + c0);
        const ushort8 v1 = *(const ushort8*)(H + (size_t)s1 * D + c0);
        const ushort8 v2 = *(const ushort8*)(H + (size_t)s2 * D + c0);
        const ushort8 v3 = *(const ushort8*)(H + (size_t)s3 * D + c0);
#pragma unroll
        for (int e = 0; e < 8; ++e) {
            acc[e] += b2f(v0[e]);
            acc[e] += b2f(v1[e]);
            acc[e] += b2f(v2[e]);
            acc[e] += b2f(v3[e]);
        }
    }
    for (; j < e1; ++j) {
        const int s = csr_src[j];
        const ushort8 v = *(const ushort8*)(H + (size_t)s * D + c0);
#pragma unroll
        for (int e = 0; e < 8; ++e) acc[e] += b2f(v[e]);
    }

    const float di = dinv[n];
#pragma unroll
    for (int e = 0; e < 8; ++e) {
        float t = fmaf(acc[e], di, bias[c0 + e]);
        acc[e] = t > 0.f ? t : expf(t) - 1.f;
    }

    if (BF16_OUT) {
        ushort8 o;
#pragma unroll
        for (int e = 0; e < 8; ++e) o[e] = f2b(acc[e]);
        *(ushort8*)((unsigned short*)outv + (size_t)n * D + c0) = o;
    } else {
        float* orow = (float*)outv + (size_t)n * D + c0;
        *(float4*)orow = make_float4(acc[0], acc[1], acc[2], acc[3]);
        *(float4*)(orow + 4) = make_float4(acc[4], acc[5], acc[6], acc[7]);
    }
}

// ---------------- launch ----------------

extern "C" void kernel_launch(void* const* d_in, const int* in_sizes, int n_in,
                              void* d_out, int out_size, void* d_ws, size_t ws_size,
                              hipStream_t stream) {
    const float* x  = (const float*)d_in[0];
    const int* ei   = (const int*)d_in[1];
    const int* src  = ei;
    const int* dst  = ei + N_EDGES;
    const float* W1 = (const float*)d_in[2];
    const float* b1 = (const float*)d_in[3];
    const float* W2 = (const float*)d_in[4];
    const float* b2 = (const float*)d_in[5];
    float* out = (float*)d_out;

    char* ws = (char*)d_ws;
    size_t off = 0;
    auto alloc = [&](size_t bytes) -> void* {
        void* p = ws + off;
        off = (off + bytes + 255) & ~(size_t)255;
        return p;
    };
    int*   indeg     = (int*)alloc((size_t)N_NODES * 4);
    int*   bsum      = (int*)alloc((size_t)NB * 4);
    int*   boff      = (int*)alloc((size_t)NB * 4);
    int*   row_start = (int*)alloc((size_t)(N_NODES + 1) * 4);
    int*   cursor    = (int*)alloc((size_t)N_NODES * 4);
    int*   csr_src   = (int*)alloc((size_t)N_EDGES * 4);
    float* dinv      = (float*)alloc((size_t)N_NODES * 4);
    unsigned short* W1t  = (unsigned short*)alloc((size_t)D_H * D_IN * 2);
    unsigned short* W2t  = (unsigned short*)alloc((size_t)D_OUT * D_H * 2);
    unsigned short* H1   = (unsigned short*)alloc((size_t)N_NODES * D_H * 2);   // 51.2 MB
    unsigned short* out1 = (unsigned short*)alloc((size_t)N_NODES * D_H * 2);   // 51.2 MB
    unsigned short* H2   = (unsigned short*)alloc((size_t)N_NODES * D_OUT * 2); // 25.6 MB

    // L0: zero indeg (must precede atomics)
    k_zero<<<NB, 256, 0, stream>>>(indeg, N_NODES);
    // L1: fused indeg-hist + weight transposes
    k_prep<<<NBK + W1B + W2B, 256, 0, stream>>>(W1, W1t, W2, W2t, dst, indeg);
    // L2-4: scan chain -> row_start/cursor/dinv
    k_partials<<<NB, 256, 0, stream>>>(indeg, bsum);
    k_scanb<<<1, 256, 0, stream>>>(bsum, boff);
    k_finalize<<<NB, 256, 0, stream>>>(indeg, boff, row_start, cursor, dinv);

    const int nrb = (N_NODES + 127) / 128;  // 391
    const int rgrp = (nrb + 7) / 8;         // 49

    // ----- layer 1 (A = x fp32 direct; bucket fused into GEMM1 launch) -----
    {
        const int ncb = D_H / 128;          // 4
        k_gemm<true, true><<<NBK + 8 * ncb * rgrp, 256, 0, stream>>>(
            x, W1t, H1, dinv, N_NODES, D_H, D_IN, ncb, nrb, src, dst, cursor, csr_src);
    }
    k_aggregate<512, true><<<(N_NODES + 3) / 4, 256, 0, stream>>>(H1, b1, out1, row_start, csr_src, dinv);

    // ----- layer 2 -----
    {
        const int ncb = D_OUT / 128;        // 2
        k_gemm<false, false><<<8 * ncb * rgrp, 256, 0, stream>>>(
            out1, W2t, H2, dinv, N_NODES, D_OUT, D_H, ncb, nrb, nullptr, nullptr, nullptr, nullptr);
    }
    k_aggregate<256, false><<<(N_NODES + 7) / 8, 256, 0, stream>>>(H2, b2, out, row_start, csr_src, dinv);
}